// Round 19
// baseline (179.311 us; speedup 1.0000x reference)
//
#include <hip/hip_runtime.h>
#include <hip/hip_fp16.h>
#include <hip/hip_cooperative_groups.h>

typedef unsigned int u32;
typedef unsigned short u16;
typedef __attribute__((ext_vector_type(8))) short bf16x8;
typedef __attribute__((ext_vector_type(4))) float f32x4;

#define WS_ALIGN(x) (((x) + 255) & ~(size_t)255)
#define DEG_STRIDE 8   // ints: 32B counter spacing -> 8x less line contention

__device__ inline u16 f2bf(float f) {
    u32 u = __float_as_uint(f);
    u32 r = (u + 0x7fffu + ((u >> 16) & 1u)) >> 16;   // RNE
    return (u16)r;
}

// prep: zero padded counters (int4) + W f32 -> Wh bf16
__global__ void prep_kernel(const float* __restrict__ W, uint2* __restrict__ Wh,
                            int4* __restrict__ degp4, int n4) {
    int t = blockIdx.x * 256 + threadIdx.x;
    if (t < n4) degp4[t] = make_int4(0, 0, 0, 0);
    if (t < 4096) {
        float4 v = ((const float4*)W)[t];
        Wh[t] = make_uint2((u32)f2bf(v.x) | ((u32)f2bf(v.y) << 16),
                           (u32)f2bf(v.z) | ((u32)f2bf(v.w) << 16));
    }
}

// Shared gemm body: one wave = 32 nodes (2 m-tiles) of batch b.
// Swapped operands: A=W rows, B=x rows; identical A/B k-maps cancel the HW
// k-permutation (validated r7/r9/r10). D (m89): col=lane&15 (node), row=g*4+reg.
__device__ __forceinline__ void gemm_body(const float* __restrict__ x,
                                          const u16* __restrict__ Wh,
                                          u16* __restrict__ yh,
                                          int N, int b, int gbid, int tid) {
    int wv = gbid * 4 + (tid >> 6);
    int r0 = wv * 32;
    if (r0 >= N) return;
    int lane = tid & 63;
    int l15 = lane & 15, g = lane >> 4;

    bf16x8 xb[2][4];
#pragma unroll
    for (int m = 0; m < 2; ++m) {
        int xrow = r0 + m * 16 + l15;
        if (xrow >= N) xrow = N - 1;      // safe clamp (store is guarded)
        const float* xp = x + ((size_t)b * N + xrow) * 128 + g * 8;
#pragma unroll
        for (int kt = 0; kt < 4; ++kt) {
            float4 u0 = *(const float4*)(xp + kt * 32);
            float4 u1 = *(const float4*)(xp + kt * 32 + 4);
            bf16x8 t;
            t[0] = (short)f2bf(u0.x); t[1] = (short)f2bf(u0.y);
            t[2] = (short)f2bf(u0.z); t[3] = (short)f2bf(u0.w);
            t[4] = (short)f2bf(u1.x); t[5] = (short)f2bf(u1.y);
            t[6] = (short)f2bf(u1.z); t[7] = (short)f2bf(u1.w);
            xb[m][kt] = t;
        }
    }

    int n0 = r0 + l15, n1 = r0 + 16 + l15;
    u16* yp0 = yh + (size_t)n0 * 256 + b * 128 + g * 4;
    u16* yp1 = yh + (size_t)n1 * 256 + b * 128 + g * 4;
#pragma unroll
    for (int ct = 0; ct < 8; ++ct) {
        const u16* wp = Wh + (size_t)(ct * 16 + l15) * 128 + g * 8;
        f32x4 a0 = {0.f, 0.f, 0.f, 0.f};
        f32x4 a1 = {0.f, 0.f, 0.f, 0.f};
#pragma unroll
        for (int kt = 0; kt < 4; ++kt) {
            bf16x8 wf = *(const bf16x8*)(wp + kt * 32);
            a0 = __builtin_amdgcn_mfma_f32_16x16x32_bf16(wf, xb[0][kt], a0, 0, 0, 0);
            a1 = __builtin_amdgcn_mfma_f32_16x16x32_bf16(wf, xb[1][kt], a1, 0, 0, 0);
        }
        if (n0 < N) {
            u32 lo = (u32)f2bf(a0[0]) | ((u32)f2bf(a0[1]) << 16);
            u32 hi = (u32)f2bf(a0[2]) | ((u32)f2bf(a0[3]) << 16);
            *(uint2*)(yp0 + ct * 16) = make_uint2(lo, hi);
        }
        if (n1 < N) {
            u32 lo = (u32)f2bf(a1[0]) | ((u32)f2bf(a1[1]) << 16);
            u32 hi = (u32)f2bf(a1[2]) | ((u32)f2bf(a1[3]) << 16);
            *(uint2*)(yp1 + ct * 16) = make_uint2(lo, hi);
        }
    }
}

// Kernel A: gemm(batch 0) || deg histogram (padded counters).
__global__ __launch_bounds__(256) void kernelA(const float* __restrict__ x,
                                               const u16* __restrict__ Wh,
                                               const int* __restrict__ dst,
                                               int* __restrict__ degp,
                                               u16* __restrict__ yh,
                                               int N, int E, int gpb) {
    int bid = blockIdx.x;
    if (bid < gpb) {
        gemm_body(x, Wh, yh, N, 0, bid, threadIdx.x);
    } else {
        int e0 = ((bid - gpb) * 256 + threadIdx.x) * 4;
        if (e0 + 3 < E) {
            int4 d4 = *(const int4*)(dst + e0);
            atomicAdd(&degp[d4.x * DEG_STRIDE], 1);
            atomicAdd(&degp[d4.y * DEG_STRIDE], 1);
            atomicAdd(&degp[d4.z * DEG_STRIDE], 1);
            atomicAdd(&degp[d4.w * DEG_STRIDE], 1);
        } else {
            for (int e = e0; e < E; ++e) atomicAdd(&degp[dst[e] * DEG_STRIDE], 1);
        }
    }
}

// Fused scan (cooperative, nb<=256 blocks co-resident): phase 1 block sums +
// stash local values/prefix in registers; grid.sync; phase 2 scan block sums
// in LDS, write rowptr/dis and exclusive offsets in place into degp (cursor).
__global__ void scan_kernel(int* __restrict__ degp, int* __restrict__ bsum,
                            int* __restrict__ rowptr, float* __restrict__ dis,
                            int N, int nb) {
    __shared__ int tmp[256];
    __shared__ int bs[256];
    int tid = threadIdx.x;
    int i0 = blockIdx.x * 1024 + tid * 4;

    int v0 = (i0 < N) ? degp[i0 * DEG_STRIDE] : 0;
    int v1 = (i0 + 1 < N) ? degp[(i0 + 1) * DEG_STRIDE] : 0;
    int v2 = (i0 + 2 < N) ? degp[(i0 + 2) * DEG_STRIDE] : 0;
    int v3 = (i0 + 3 < N) ? degp[(i0 + 3) * DEG_STRIDE] : 0;
    int s = v0 + v1 + v2 + v3;
    tmp[tid] = s;
    __syncthreads();
    for (int off = 1; off < 256; off <<= 1) {
        int t = (tid >= off) ? tmp[tid - off] : 0;
        __syncthreads();
        tmp[tid] += t;
        __syncthreads();
    }
    int lexcl = tmp[tid] - s;                 // local exclusive prefix
    if (tid == 255) bsum[blockIdx.x] = tmp[255];
    __threadfence();
    cooperative_groups::this_grid().sync();

    bs[tid] = (tid < nb) ? bsum[tid] : 0;
    __syncthreads();
    for (int off = 1; off < 256; off <<= 1) {
        int t = (tid >= off) ? bs[tid - off] : 0;
        __syncthreads();
        bs[tid] += t;
        __syncthreads();
    }
    int boff = bs[blockIdx.x] - ((blockIdx.x < nb) ? bsum[blockIdx.x] : 0);

    int e0 = lexcl + boff;
    int e1 = e0 + v0, e2 = e1 + v1, e3 = e2 + v2;
    if (i0 < N) {
        rowptr[i0] = e0; degp[i0 * DEG_STRIDE] = e0;
        dis[i0] = rsqrtf((float)(v0 < 1 ? 1 : v0));
        if (i0 == N - 1) rowptr[N] = e1;
    }
    if (i0 + 1 < N) {
        rowptr[i0 + 1] = e1; degp[(i0 + 1) * DEG_STRIDE] = e1;
        dis[i0 + 1] = rsqrtf((float)(v1 < 1 ? 1 : v1));
        if (i0 + 1 == N - 1) rowptr[N] = e2;
    }
    if (i0 + 2 < N) {
        rowptr[i0 + 2] = e2; degp[(i0 + 2) * DEG_STRIDE] = e2;
        dis[i0 + 2] = rsqrtf((float)(v2 < 1 ? 1 : v2));
        if (i0 + 2 == N - 1) rowptr[N] = e3;
    }
    if (i0 + 3 < N) {
        rowptr[i0 + 3] = e3; degp[(i0 + 3) * DEG_STRIDE] = e3;
        dis[i0 + 3] = rsqrtf((float)(v3 < 1 ? 1 : v3));
        if (i0 + 3 == N - 1) rowptr[N] = e3 + v3;
    }
}

// Kernel B: gemm(batch 1) || fill (padded cursor).
// csr entry: 4B packed = (fp16(norm) << 16) | src  (src < 65536; N=50000).
__global__ __launch_bounds__(256) void kernelB(const float* __restrict__ x,
                                               const u16* __restrict__ Wh,
                                               const int* __restrict__ src,
                                               const int* __restrict__ dst,
                                               const float* __restrict__ ew,
                                               const float* __restrict__ dis,
                                               int* __restrict__ degp,
                                               u32* __restrict__ csr,
                                               u16* __restrict__ yh,
                                               int N, int E, int gpb) {
    int bid = blockIdx.x;
    if (bid < gpb) {
        gemm_body(x, Wh, yh, N, 1, bid, threadIdx.x);
    } else {
        int e0 = ((bid - gpb) * 256 + threadIdx.x) * 4;
        if (e0 + 3 < E) {
            int4 s4 = *(const int4*)(src + e0);
            int4 d4 = *(const int4*)(dst + e0);
            float4 w4 = *(const float4*)(ew + e0);
            {
                float nm = dis[s4.x] * w4.x * dis[d4.x];
                int pos = atomicAdd(&degp[d4.x * DEG_STRIDE], 1);
                csr[pos] = ((u32)__half_as_ushort(__float2half_rn(nm)) << 16) | (u32)s4.x;
            }
            {
                float nm = dis[s4.y] * w4.y * dis[d4.y];
                int pos = atomicAdd(&degp[d4.y * DEG_STRIDE], 1);
                csr[pos] = ((u32)__half_as_ushort(__float2half_rn(nm)) << 16) | (u32)s4.y;
            }
            {
                float nm = dis[s4.z] * w4.z * dis[d4.z];
                int pos = atomicAdd(&degp[d4.z * DEG_STRIDE], 1);
                csr[pos] = ((u32)__half_as_ushort(__float2half_rn(nm)) << 16) | (u32)s4.z;
            }
            {
                float nm = dis[s4.w] * w4.w * dis[d4.w];
                int pos = atomicAdd(&degp[d4.w * DEG_STRIDE], 1);
                csr[pos] = ((u32)__half_as_ushort(__float2half_rn(nm)) << 16) | (u32)s4.w;
            }
        } else {
            for (int e = e0; e < E; ++e) {
                int s = src[e], d = dst[e];
                float nm = dis[s] * ew[e] * dis[d];
                int pos = atomicAdd(&degp[d * DEG_STRIDE], 1);
                csr[pos] = ((u32)__half_as_ushort(__float2half_rn(nm)) << 16) | (u32)s;
            }
        }
    }
}

// One WAVE per (node, batch): grid (N, 2). Batch-phased dispatch -> 12.8MB
// working set/phase. Uniform CSR indexing (scalar s_loads). 16-deep MLP.
__global__ __launch_bounds__(64) void agg_kernel(const u32* __restrict__ yh,
                                                 const int* __restrict__ rowptr,
                                                 const u32* __restrict__ csr,
                                                 const float* __restrict__ bias,
                                                 float* __restrict__ out, int N) {
    int node = blockIdx.x;
    int b = blockIdx.y;
    int lane = threadIdx.x;                 // 0..63
    const u32* xb = yh + (size_t)b * 64 + lane;   // + node*128 (u32 units)
    int beg = rowptr[node], end = rowptr[node + 1];
    float2 acc = make_float2(0.f, 0.f);

    int j0 = beg;
    for (; j0 + 16 <= end; j0 += 16) {
        u32 pv[16];
#pragma unroll
        for (int j = 0; j < 16; ++j) pv[j] = csr[j0 + j];     // uniform -> s_load
        u32 q[16];
#pragma unroll
        for (int j = 0; j < 16; ++j) q[j] = xb[(size_t)(pv[j] & 0xffffu) * 128];
#pragma unroll
        for (int j = 0; j < 16; ++j) {
            float nm = __half2float(__ushort_as_half((u16)(pv[j] >> 16)));
            acc.x = fmaf(__uint_as_float(q[j] << 16), nm, acc.x);
            acc.y = fmaf(__uint_as_float(q[j] & 0xffff0000u), nm, acc.y);
        }
    }
    for (; j0 + 4 <= end; j0 += 4) {
        u32 pv[4];
#pragma unroll
        for (int j = 0; j < 4; ++j) pv[j] = csr[j0 + j];
        u32 q[4];
#pragma unroll
        for (int j = 0; j < 4; ++j) q[j] = xb[(size_t)(pv[j] & 0xffffu) * 128];
#pragma unroll
        for (int j = 0; j < 4; ++j) {
            float nm = __half2float(__ushort_as_half((u16)(pv[j] >> 16)));
            acc.x = fmaf(__uint_as_float(q[j] << 16), nm, acc.x);
            acc.y = fmaf(__uint_as_float(q[j] & 0xffff0000u), nm, acc.y);
        }
    }
    for (; j0 < end; ++j0) {
        u32 pv = csr[j0];
        float nm = __half2float(__ushort_as_half((u16)(pv >> 16)));
        u32 v = xb[(size_t)(pv & 0xffffu) * 128];
        acc.x = fmaf(__uint_as_float(v << 16), nm, acc.x);
        acc.y = fmaf(__uint_as_float(v & 0xffff0000u), nm, acc.y);
    }

    float2 bv = *(const float2*)(bias + lane * 2);
    acc.x += bv.x; acc.y += bv.y;
    *(float2*)(out + ((size_t)b * N + node) * 128 + lane * 2) = acc;
}

extern "C" void kernel_launch(void* const* d_in, const int* in_sizes, int n_in,
                              void* d_out, int out_size, void* d_ws, size_t ws_size,
                              hipStream_t stream) {
    const float* x    = (const float*)d_in[0];
    const int*   eidx = (const int*)d_in[1];   // [2][E] flat: src then dst
    const float* ew   = (const float*)d_in[2];
    const float* W    = (const float*)d_in[3];
    const float* bias = (const float*)d_in[4];
    float* out = (float*)d_out;

    const int E = in_sizes[2];                 // edge_weight count
    const int N = in_sizes[0] / 256;           // B=2, F=128 -> N = size/(2*128)
    const int nb = (N + 1023) / 1024;          // scan blocks (must be <= 256)

    const int* srcp = eidx;
    const int* dstp = eidx + E;

    // ws footprint ~31 MB — within round-3-proven envelope. DO NOT GROW (round-6 overflow).
    char* w = (char*)d_ws;
    int*   degp   = (int*)w;   w += WS_ALIGN((size_t)N * DEG_STRIDE * 4);  // padded counters/cursor
    int*   rowptr = (int*)w;   w += WS_ALIGN((size_t)(N + 1) * 4);
    float* dis    = (float*)w; w += WS_ALIGN((size_t)N * 4);
    int*   bsum   = (int*)w;   w += WS_ALIGN((size_t)nb * 4);
    u32*   csr    = (u32*)w;   w += WS_ALIGN((size_t)E * 4);        // packed 4B/edge
    u16*   yh     = (u16*)w;   w += WS_ALIGN((size_t)N * 512);      // [N][2][128] bf16
    uint2* Wh     = (uint2*)w; w += WS_ALIGN((size_t)128 * 128 * 2);

    int n4 = (N * DEG_STRIDE) / 4;             // int4 count for zeroing
    int pblk = (n4 > 4096 ? n4 : 4096);
    hipLaunchKernelGGL(prep_kernel, dim3((pblk + 255) / 256), dim3(256), 0, stream,
                       W, Wh, (int4*)degp, n4);
    int gpb = ((N + 31) / 32 + 3) / 4;                    // gemm blocks per batch
    int eBlocks = ((E + 3) / 4 + 255) / 256;
    hipLaunchKernelGGL(kernelA, dim3(gpb + eBlocks), dim3(256), 0, stream,
                       x, (const u16*)Wh, dstp, degp, yh, N, E, gpb);
    {
        int Nv = N, nbv = nb;
        int* degp_a = degp; int* bsum_a = bsum; int* rowptr_a = rowptr; float* dis_a = dis;
        void* args[] = {&degp_a, &bsum_a, &rowptr_a, &dis_a, &Nv, &nbv};
        hipLaunchCooperativeKernel((void*)scan_kernel, dim3(nb), dim3(256), args, 0, stream);
    }
    hipLaunchKernelGGL(kernelB, dim3(gpb + eBlocks), dim3(256), 0, stream,
                       x, (const u16*)Wh, srcp, dstp, ew, dis, degp, csr, yh, N, E, gpb);
    hipLaunchKernelGGL(agg_kernel,  dim3(N, 2), dim3(64), 0, stream,
                       (const u32*)yh, rowptr, csr, bias, out, N);
}

// Round 21
// 160.160 us; speedup vs baseline: 1.1196x; 1.1196x over previous
//
#include <hip/hip_runtime.h>
#include <hip/hip_fp16.h>

typedef unsigned int u32;
typedef unsigned short u16;
typedef __attribute__((ext_vector_type(8))) short bf16x8;
typedef __attribute__((ext_vector_type(4))) float f32x4;

#define WS_ALIGN(x) (((x) + 255) & ~(size_t)255)
#define DEG_STRIDE 8   // ints: 32B counter spacing -> 8x less line contention

__device__ inline u16 f2bf(float f) {
    u32 u = __float_as_uint(f);
    u32 r = (u + 0x7fffu + ((u >> 16) & 1u)) >> 16;   // RNE
    return (u16)r;
}

// prep: zero padded counters (int4) + W f32 -> Wh bf16 + zero scan-done flag
__global__ void prep_kernel(const float* __restrict__ W, uint2* __restrict__ Wh,
                            int4* __restrict__ degp4, int n4, int* __restrict__ done) {
    int t = blockIdx.x * 256 + threadIdx.x;
    if (t == 0) *done = 0;
    if (t < n4) degp4[t] = make_int4(0, 0, 0, 0);
    if (t < 4096) {
        float4 v = ((const float4*)W)[t];
        Wh[t] = make_uint2((u32)f2bf(v.x) | ((u32)f2bf(v.y) << 16),
                           (u32)f2bf(v.z) | ((u32)f2bf(v.w) << 16));
    }
}

// Shared gemm body: one wave = 32 nodes (2 m-tiles) of batch b.
// Swapped operands: A=W rows, B=x rows; identical A/B k-maps cancel the HW
// k-permutation (validated r7/r9/r10). D (m89): col=lane&15 (node), row=g*4+reg.
__device__ __forceinline__ void gemm_body(const float* __restrict__ x,
                                          const u16* __restrict__ Wh,
                                          u16* __restrict__ yh,
                                          int N, int b, int gbid, int tid) {
    int wv = gbid * 4 + (tid >> 6);
    int r0 = wv * 32;
    if (r0 >= N) return;
    int lane = tid & 63;
    int l15 = lane & 15, g = lane >> 4;

    bf16x8 xb[2][4];
#pragma unroll
    for (int m = 0; m < 2; ++m) {
        int xrow = r0 + m * 16 + l15;
        if (xrow >= N) xrow = N - 1;      // safe clamp (store is guarded)
        const float* xp = x + ((size_t)b * N + xrow) * 128 + g * 8;
#pragma unroll
        for (int kt = 0; kt < 4; ++kt) {
            float4 u0 = *(const float4*)(xp + kt * 32);
            float4 u1 = *(const float4*)(xp + kt * 32 + 4);
            bf16x8 t;
            t[0] = (short)f2bf(u0.x); t[1] = (short)f2bf(u0.y);
            t[2] = (short)f2bf(u0.z); t[3] = (short)f2bf(u0.w);
            t[4] = (short)f2bf(u1.x); t[5] = (short)f2bf(u1.y);
            t[6] = (short)f2bf(u1.z); t[7] = (short)f2bf(u1.w);
            xb[m][kt] = t;
        }
    }

    int n0 = r0 + l15, n1 = r0 + 16 + l15;
    u16* yp0 = yh + (size_t)n0 * 256 + b * 128 + g * 4;
    u16* yp1 = yh + (size_t)n1 * 256 + b * 128 + g * 4;
#pragma unroll
    for (int ct = 0; ct < 8; ++ct) {
        const u16* wp = Wh + (size_t)(ct * 16 + l15) * 128 + g * 8;
        f32x4 a0 = {0.f, 0.f, 0.f, 0.f};
        f32x4 a1 = {0.f, 0.f, 0.f, 0.f};
#pragma unroll
        for (int kt = 0; kt < 4; ++kt) {
            bf16x8 wf = *(const bf16x8*)(wp + kt * 32);
            a0 = __builtin_amdgcn_mfma_f32_16x16x32_bf16(wf, xb[0][kt], a0, 0, 0, 0);
            a1 = __builtin_amdgcn_mfma_f32_16x16x32_bf16(wf, xb[1][kt], a1, 0, 0, 0);
        }
        if (n0 < N) {
            u32 lo = (u32)f2bf(a0[0]) | ((u32)f2bf(a0[1]) << 16);
            u32 hi = (u32)f2bf(a0[2]) | ((u32)f2bf(a0[3]) << 16);
            *(uint2*)(yp0 + ct * 16) = make_uint2(lo, hi);
        }
        if (n1 < N) {
            u32 lo = (u32)f2bf(a1[0]) | ((u32)f2bf(a1[1]) << 16);
            u32 hi = (u32)f2bf(a1[2]) | ((u32)f2bf(a1[3]) << 16);
            *(uint2*)(yp1 + ct * 16) = make_uint2(lo, hi);
        }
    }
}

// Kernel A: gemm(batch 0) || deg histogram (padded counters).
__global__ __launch_bounds__(256) void kernelA(const float* __restrict__ x,
                                               const u16* __restrict__ Wh,
                                               const int* __restrict__ dst,
                                               int* __restrict__ degp,
                                               u16* __restrict__ yh,
                                               int N, int E, int gpb) {
    int bid = blockIdx.x;
    if (bid < gpb) {
        gemm_body(x, Wh, yh, N, 0, bid, threadIdx.x);
    } else {
        int e0 = ((bid - gpb) * 256 + threadIdx.x) * 4;
        if (e0 + 3 < E) {
            int4 d4 = *(const int4*)(dst + e0);
            atomicAdd(&degp[d4.x * DEG_STRIDE], 1);
            atomicAdd(&degp[d4.y * DEG_STRIDE], 1);
            atomicAdd(&degp[d4.z * DEG_STRIDE], 1);
            atomicAdd(&degp[d4.w * DEG_STRIDE], 1);
        } else {
            for (int e = e0; e < E; ++e) atomicAdd(&degp[dst[e] * DEG_STRIDE], 1);
        }
    }
}

// Fused scan, spin-sync (NOT cooperative API — r19 showed coop launch costs
// ~20µs under graph capture). nb<=49 blocks x 256 threads on a 256-CU chip are
// physically co-resident -> device-scope atomic barrier is safe; `done` is
// re-zeroed by prep each launch (no cross-call state). Phase 1: block sums,
// local prefix kept in registers. Barrier. Phase 2: scan block sums (atomic
// reads - L1-staleness proof), write rowptr/dis + exclusive offsets in place
// into degp (cursor).
__global__ __launch_bounds__(256) void scan_kernel(int* __restrict__ degp,
                                                   int* __restrict__ bsum,
                                                   int* __restrict__ rowptr,
                                                   float* __restrict__ dis,
                                                   int* __restrict__ done,
                                                   int N, int nb) {
    __shared__ int tmp[256];
    __shared__ int bs[256];
    int tid = threadIdx.x;
    int i0 = blockIdx.x * 1024 + tid * 4;

    int v0 = (i0 < N) ? degp[i0 * DEG_STRIDE] : 0;
    int v1 = (i0 + 1 < N) ? degp[(i0 + 1) * DEG_STRIDE] : 0;
    int v2 = (i0 + 2 < N) ? degp[(i0 + 2) * DEG_STRIDE] : 0;
    int v3 = (i0 + 3 < N) ? degp[(i0 + 3) * DEG_STRIDE] : 0;
    int s = v0 + v1 + v2 + v3;
    tmp[tid] = s;
    __syncthreads();
    for (int off = 1; off < 256; off <<= 1) {
        int t = (tid >= off) ? tmp[tid - off] : 0;
        __syncthreads();
        tmp[tid] += t;
        __syncthreads();
    }
    int lexcl = tmp[tid] - s;                 // local exclusive prefix (registers)
    int bsumOwn = tmp[255];                   // this block's total
    if (tid == 255) bsum[blockIdx.x] = bsumOwn;
    __threadfence();                          // publish bsum device-wide
    __syncthreads();
    if (tid == 0) {
        atomicAdd(done, 1);
        while (atomicAdd(done, 0) < nb) { }   // all blocks co-resident
    }
    __syncthreads();
    __threadfence();                          // acquire side

    bs[tid] = (tid < nb) ? atomicAdd(&bsum[tid], 0) : 0;   // fresh device reads
    __syncthreads();
    for (int off = 1; off < 256; off <<= 1) {
        int t = (tid >= off) ? bs[tid - off] : 0;
        __syncthreads();
        bs[tid] += t;
        __syncthreads();
    }
    int boff = bs[blockIdx.x] - bsumOwn;      // exclusive prefix of block sums

    int e0 = lexcl + boff;
    int e1 = e0 + v0, e2 = e1 + v1, e3 = e2 + v2;
    if (i0 < N) {
        rowptr[i0] = e0; degp[i0 * DEG_STRIDE] = e0;
        dis[i0] = rsqrtf((float)(v0 < 1 ? 1 : v0));
        if (i0 == N - 1) rowptr[N] = e1;
    }
    if (i0 + 1 < N) {
        rowptr[i0 + 1] = e1; degp[(i0 + 1) * DEG_STRIDE] = e1;
        dis[i0 + 1] = rsqrtf((float)(v1 < 1 ? 1 : v1));
        if (i0 + 1 == N - 1) rowptr[N] = e2;
    }
    if (i0 + 2 < N) {
        rowptr[i0 + 2] = e2; degp[(i0 + 2) * DEG_STRIDE] = e2;
        dis[i0 + 2] = rsqrtf((float)(v2 < 1 ? 1 : v2));
        if (i0 + 2 == N - 1) rowptr[N] = e3;
    }
    if (i0 + 3 < N) {
        rowptr[i0 + 3] = e3; degp[(i0 + 3) * DEG_STRIDE] = e3;
        dis[i0 + 3] = rsqrtf((float)(v3 < 1 ? 1 : v3));
        if (i0 + 3 == N - 1) rowptr[N] = e3 + v3;
    }
}

// Kernel B: gemm(batch 1) || fill (padded cursor).
// csr entry: 4B packed = (fp16(norm) << 16) | src  (src < 65536; N=50000).
__global__ __launch_bounds__(256) void kernelB(const float* __restrict__ x,
                                               const u16* __restrict__ Wh,
                                               const int* __restrict__ src,
                                               const int* __restrict__ dst,
                                               const float* __restrict__ ew,
                                               const float* __restrict__ dis,
                                               int* __restrict__ degp,
                                               u32* __restrict__ csr,
                                               u16* __restrict__ yh,
                                               int N, int E, int gpb) {
    int bid = blockIdx.x;
    if (bid < gpb) {
        gemm_body(x, Wh, yh, N, 1, bid, threadIdx.x);
    } else {
        int e0 = ((bid - gpb) * 256 + threadIdx.x) * 4;
        if (e0 + 3 < E) {
            int4 s4 = *(const int4*)(src + e0);
            int4 d4 = *(const int4*)(dst + e0);
            float4 w4 = *(const float4*)(ew + e0);
            {
                float nm = dis[s4.x] * w4.x * dis[d4.x];
                int pos = atomicAdd(&degp[d4.x * DEG_STRIDE], 1);
                csr[pos] = ((u32)__half_as_ushort(__float2half_rn(nm)) << 16) | (u32)s4.x;
            }
            {
                float nm = dis[s4.y] * w4.y * dis[d4.y];
                int pos = atomicAdd(&degp[d4.y * DEG_STRIDE], 1);
                csr[pos] = ((u32)__half_as_ushort(__float2half_rn(nm)) << 16) | (u32)s4.y;
            }
            {
                float nm = dis[s4.z] * w4.z * dis[d4.z];
                int pos = atomicAdd(&degp[d4.z * DEG_STRIDE], 1);
                csr[pos] = ((u32)__half_as_ushort(__float2half_rn(nm)) << 16) | (u32)s4.z;
            }
            {
                float nm = dis[s4.w] * w4.w * dis[d4.w];
                int pos = atomicAdd(&degp[d4.w * DEG_STRIDE], 1);
                csr[pos] = ((u32)__half_as_ushort(__float2half_rn(nm)) << 16) | (u32)s4.w;
            }
        } else {
            for (int e = e0; e < E; ++e) {
                int s = src[e], d = dst[e];
                float nm = dis[s] * ew[e] * dis[d];
                int pos = atomicAdd(&degp[d * DEG_STRIDE], 1);
                csr[pos] = ((u32)__half_as_ushort(__float2half_rn(nm)) << 16) | (u32)s;
            }
        }
    }
}

// One WAVE per (node, batch): grid (N, 2). Batch-phased dispatch -> 12.8MB
// working set/phase. Uniform CSR indexing (scalar s_loads). 8-deep MLP.
// STRUCTURALLY DONE (r15): random-256B gather plateau ~4 TB/s.
__global__ __launch_bounds__(64) void agg_kernel(const u32* __restrict__ yh,
                                                 const int* __restrict__ rowptr,
                                                 const u32* __restrict__ csr,
                                                 const float* __restrict__ bias,
                                                 float* __restrict__ out, int N) {
    int node = blockIdx.x;
    int b = blockIdx.y;
    int lane = threadIdx.x;                 // 0..63
    const u32* xb = yh + (size_t)b * 64 + lane;   // + node*128 (u32 units)
    int beg = rowptr[node], end = rowptr[node + 1];
    float2 acc = make_float2(0.f, 0.f);

    int j0 = beg;
    for (; j0 + 8 <= end; j0 += 8) {
        u32 pv[8];
#pragma unroll
        for (int j = 0; j < 8; ++j) pv[j] = csr[j0 + j];      // uniform -> s_load
        u32 q[8];
#pragma unroll
        for (int j = 0; j < 8; ++j) q[j] = xb[(size_t)(pv[j] & 0xffffu) * 128];
#pragma unroll
        for (int j = 0; j < 8; ++j) {
            float nm = __half2float(__ushort_as_half((u16)(pv[j] >> 16)));
            acc.x = fmaf(__uint_as_float(q[j] << 16), nm, acc.x);
            acc.y = fmaf(__uint_as_float(q[j] & 0xffff0000u), nm, acc.y);
        }
    }
    for (; j0 < end; ++j0) {
        u32 pv = csr[j0];
        float nm = __half2float(__ushort_as_half((u16)(pv >> 16)));
        u32 v = xb[(size_t)(pv & 0xffffu) * 128];
        acc.x = fmaf(__uint_as_float(v << 16), nm, acc.x);
        acc.y = fmaf(__uint_as_float(v & 0xffff0000u), nm, acc.y);
    }

    float2 bv = *(const float2*)(bias + lane * 2);
    acc.x += bv.x; acc.y += bv.y;
    *(float2*)(out + ((size_t)b * N + node) * 128 + lane * 2) = acc;
}

extern "C" void kernel_launch(void* const* d_in, const int* in_sizes, int n_in,
                              void* d_out, int out_size, void* d_ws, size_t ws_size,
                              hipStream_t stream) {
    const float* x    = (const float*)d_in[0];
    const int*   eidx = (const int*)d_in[1];   // [2][E] flat: src then dst
    const float* ew   = (const float*)d_in[2];
    const float* W    = (const float*)d_in[3];
    const float* bias = (const float*)d_in[4];
    float* out = (float*)d_out;

    const int E = in_sizes[2];                 // edge_weight count
    const int N = in_sizes[0] / 256;           // B=2, F=128 -> N = size/(2*128)
    const int nb = (N + 1023) / 1024;          // scan blocks (must be <= 256)

    const int* srcp = eidx;
    const int* dstp = eidx + E;

    // ws footprint ~31 MB — within round-3-proven envelope. DO NOT GROW (round-6 overflow).
    char* w = (char*)d_ws;
    int*   degp   = (int*)w;   w += WS_ALIGN((size_t)N * DEG_STRIDE * 4);  // padded counters/cursor
    int*   rowptr = (int*)w;   w += WS_ALIGN((size_t)(N + 1) * 4);
    float* dis    = (float*)w; w += WS_ALIGN((size_t)N * 4);
    int*   bsum   = (int*)w;   w += WS_ALIGN((size_t)(nb + 1) * 4);  // +1: done flag
    u32*   csr    = (u32*)w;   w += WS_ALIGN((size_t)E * 4);        // packed 4B/edge
    u16*   yh     = (u16*)w;   w += WS_ALIGN((size_t)N * 512);      // [N][2][128] bf16
    uint2* Wh     = (uint2*)w; w += WS_ALIGN((size_t)128 * 128 * 2);
    int* done = bsum + nb;

    int n4 = (N * DEG_STRIDE) / 4;             // int4 count for zeroing
    int pblk = (n4 > 4096 ? n4 : 4096);
    hipLaunchKernelGGL(prep_kernel, dim3((pblk + 255) / 256), dim3(256), 0, stream,
                       W, Wh, (int4*)degp, n4, done);
    int gpb = ((N + 31) / 32 + 3) / 4;                    // gemm blocks per batch
    int eBlocks = ((E + 3) / 4 + 255) / 256;
    hipLaunchKernelGGL(kernelA, dim3(gpb + eBlocks), dim3(256), 0, stream,
                       x, (const u16*)Wh, dstp, degp, yh, N, E, gpb);
    hipLaunchKernelGGL(scan_kernel, dim3(nb), dim3(256), 0, stream,
                       degp, bsum, rowptr, dis, done, N, nb);
    hipLaunchKernelGGL(kernelB, dim3(gpb + eBlocks), dim3(256), 0, stream,
                       x, (const u16*)Wh, srcp, dstp, ew, dis, degp, csr, yh, N, E, gpb);
    hipLaunchKernelGGL(agg_kernel,  dim3(N, 2), dim3(64), 0, stream,
                       (const u32*)yh, rowptr, csr, bias, out, N);
}

// Round 23
// 148.426 us; speedup vs baseline: 1.2081x; 1.0791x over previous
//
#include <hip/hip_runtime.h>
#include <hip/hip_fp16.h>

typedef unsigned int u32;
typedef unsigned short u16;
typedef __attribute__((ext_vector_type(8))) short bf16x8;
typedef __attribute__((ext_vector_type(4))) float f32x4;

#define WS_ALIGN(x) (((x) + 255) & ~(size_t)255)
#define DEG_STRIDE 8   // ints: 32B counter spacing -> 8x less line contention

__device__ inline u16 f2bf(float f) {
    u32 u = __float_as_uint(f);
    u32 r = (u + 0x7fffu + ((u >> 16) & 1u)) >> 16;   // RNE
    return (u16)r;
}

// prep: zero padded counters (int4) + W f32 -> Wh bf16
__global__ void prep_kernel(const float* __restrict__ W, uint2* __restrict__ Wh,
                            int4* __restrict__ degp4, int n4) {
    int t = blockIdx.x * 256 + threadIdx.x;
    if (t < n4) degp4[t] = make_int4(0, 0, 0, 0);
    if (t < 4096) {
        float4 v = ((const float4*)W)[t];
        Wh[t] = make_uint2((u32)f2bf(v.x) | ((u32)f2bf(v.y) << 16),
                           (u32)f2bf(v.z) | ((u32)f2bf(v.w) << 16));
    }
}

// Shared gemm body: one wave = 32 nodes (2 m-tiles) of batch b.
// Swapped operands: A=W rows, B=x rows; identical A/B k-maps cancel the HW
// k-permutation (validated r7/r9/r10). D (m89): col=lane&15 (node), row=g*4+reg.
__device__ __forceinline__ void gemm_body(const float* __restrict__ x,
                                          const u16* __restrict__ Wh,
                                          u16* __restrict__ yh,
                                          int N, int b, int gbid, int tid) {
    int wv = gbid * 4 + (tid >> 6);
    int r0 = wv * 32;
    if (r0 >= N) return;
    int lane = tid & 63;
    int l15 = lane & 15, g = lane >> 4;

    bf16x8 xb[2][4];
#pragma unroll
    for (int m = 0; m < 2; ++m) {
        int xrow = r0 + m * 16 + l15;
        if (xrow >= N) xrow = N - 1;      // safe clamp (store is guarded)
        const float* xp = x + ((size_t)b * N + xrow) * 128 + g * 8;
#pragma unroll
        for (int kt = 0; kt < 4; ++kt) {
            float4 u0 = *(const float4*)(xp + kt * 32);
            float4 u1 = *(const float4*)(xp + kt * 32 + 4);
            bf16x8 t;
            t[0] = (short)f2bf(u0.x); t[1] = (short)f2bf(u0.y);
            t[2] = (short)f2bf(u0.z); t[3] = (short)f2bf(u0.w);
            t[4] = (short)f2bf(u1.x); t[5] = (short)f2bf(u1.y);
            t[6] = (short)f2bf(u1.z); t[7] = (short)f2bf(u1.w);
            xb[m][kt] = t;
        }
    }

    int n0 = r0 + l15, n1 = r0 + 16 + l15;
    u16* yp0 = yh + (size_t)n0 * 256 + b * 128 + g * 4;
    u16* yp1 = yh + (size_t)n1 * 256 + b * 128 + g * 4;
#pragma unroll
    for (int ct = 0; ct < 8; ++ct) {
        const u16* wp = Wh + (size_t)(ct * 16 + l15) * 128 + g * 8;
        f32x4 a0 = {0.f, 0.f, 0.f, 0.f};
        f32x4 a1 = {0.f, 0.f, 0.f, 0.f};
#pragma unroll
        for (int kt = 0; kt < 4; ++kt) {
            bf16x8 wf = *(const bf16x8*)(wp + kt * 32);
            a0 = __builtin_amdgcn_mfma_f32_16x16x32_bf16(wf, xb[0][kt], a0, 0, 0, 0);
            a1 = __builtin_amdgcn_mfma_f32_16x16x32_bf16(wf, xb[1][kt], a1, 0, 0, 0);
        }
        if (n0 < N) {
            u32 lo = (u32)f2bf(a0[0]) | ((u32)f2bf(a0[1]) << 16);
            u32 hi = (u32)f2bf(a0[2]) | ((u32)f2bf(a0[3]) << 16);
            *(uint2*)(yp0 + ct * 16) = make_uint2(lo, hi);
        }
        if (n1 < N) {
            u32 lo = (u32)f2bf(a1[0]) | ((u32)f2bf(a1[1]) << 16);
            u32 hi = (u32)f2bf(a1[2]) | ((u32)f2bf(a1[3]) << 16);
            *(uint2*)(yp1 + ct * 16) = make_uint2(lo, hi);
        }
    }
}

// Kernel A: gemm(batch 0) || deg histogram, 1 edge/thread (4x TLP for the
// far-atomic latency chain; loads stay coalesced 4B/thread).
__global__ __launch_bounds__(256) void kernelA(const float* __restrict__ x,
                                               const u16* __restrict__ Wh,
                                               const int* __restrict__ dst,
                                               int* __restrict__ degp,
                                               u16* __restrict__ yh,
                                               int N, int E, int gpb) {
    int bid = blockIdx.x;
    if (bid < gpb) {
        gemm_body(x, Wh, yh, N, 0, bid, threadIdx.x);
    } else {
        int e = (bid - gpb) * 256 + threadIdx.x;
        if (e < E) atomicAdd(&degp[dst[e] * DEG_STRIDE], 1);
    }
}

// Block scan: per-block sums over padded deg; 4 elems/thread, Hillis-Steele.
__global__ void scan1_kernel(const int* __restrict__ degp, int* __restrict__ bsum, int N) {
    __shared__ int tmp[256];
    int tid = threadIdx.x;
    int i0 = blockIdx.x * 1024 + tid * 4;
    int s = 0;
#pragma unroll
    for (int j = 0; j < 4; ++j) if (i0 + j < N) s += degp[(i0 + j) * DEG_STRIDE];
    tmp[tid] = s;
    __syncthreads();
    for (int off = 1; off < 256; off <<= 1) {
        int t = (tid >= off) ? tmp[tid - off] : 0;
        __syncthreads();
        tmp[tid] += t;
        __syncthreads();
    }
    if (tid == 255) bsum[blockIdx.x] = tmp[255];
}

// scan3: re-scan bsum in LDS for block offset; local prefix; writes rowptr,
// dis, and the exclusive offset IN PLACE into degp (becomes fill's cursor).
__global__ void scan3_kernel(int* __restrict__ degp, const int* __restrict__ bsum,
                             int* __restrict__ rowptr, float* __restrict__ dis,
                             int N, int nb) {
    __shared__ int tmp[256];
    __shared__ int bs[256];
    int tid = threadIdx.x;
    bs[tid] = (tid < nb) ? bsum[tid] : 0;
    __syncthreads();
    for (int off = 1; off < 256; off <<= 1) {
        int t = (tid >= off) ? bs[tid - off] : 0;
        __syncthreads();
        bs[tid] += t;
        __syncthreads();
    }
    int boff = bs[blockIdx.x] - bsum[blockIdx.x];

    int i0 = blockIdx.x * 1024 + tid * 4;
    int v0 = (i0 < N) ? degp[i0 * DEG_STRIDE] : 0;
    int v1 = (i0 + 1 < N) ? degp[(i0 + 1) * DEG_STRIDE] : 0;
    int v2 = (i0 + 2 < N) ? degp[(i0 + 2) * DEG_STRIDE] : 0;
    int v3 = (i0 + 3 < N) ? degp[(i0 + 3) * DEG_STRIDE] : 0;
    int s = v0 + v1 + v2 + v3;
    tmp[tid] = s;
    __syncthreads();
    for (int off = 1; off < 256; off <<= 1) {
        int t = (tid >= off) ? tmp[tid - off] : 0;
        __syncthreads();
        tmp[tid] += t;
        __syncthreads();
    }
    int e0 = tmp[tid] - s + boff;
    int e1 = e0 + v0, e2 = e1 + v1, e3 = e2 + v2;
    if (i0 < N) {
        rowptr[i0] = e0; degp[i0 * DEG_STRIDE] = e0;
        dis[i0] = rsqrtf((float)(v0 < 1 ? 1 : v0));
        if (i0 == N - 1) rowptr[N] = e1;
    }
    if (i0 + 1 < N) {
        rowptr[i0 + 1] = e1; degp[(i0 + 1) * DEG_STRIDE] = e1;
        dis[i0 + 1] = rsqrtf((float)(v1 < 1 ? 1 : v1));
        if (i0 + 1 == N - 1) rowptr[N] = e2;
    }
    if (i0 + 2 < N) {
        rowptr[i0 + 2] = e2; degp[(i0 + 2) * DEG_STRIDE] = e2;
        dis[i0 + 2] = rsqrtf((float)(v2 < 1 ? 1 : v2));
        if (i0 + 2 == N - 1) rowptr[N] = e3;
    }
    if (i0 + 3 < N) {
        rowptr[i0 + 3] = e3; degp[(i0 + 3) * DEG_STRIDE] = e3;
        dis[i0 + 3] = rsqrtf((float)(v3 < 1 ? 1 : v3));
        if (i0 + 3 == N - 1) rowptr[N] = e3 + v3;
    }
}

// Kernel B: gemm(batch 1) || fill, 1 edge/thread (4x TLP to hide the
// dis-load -> atomicAdd -> dependent-store chain).
// csr entry: 4B packed = (fp16(norm) << 16) | src  (src < 65536; N=50000).
__global__ __launch_bounds__(256) void kernelB(const float* __restrict__ x,
                                               const u16* __restrict__ Wh,
                                               const int* __restrict__ src,
                                               const int* __restrict__ dst,
                                               const float* __restrict__ ew,
                                               const float* __restrict__ dis,
                                               int* __restrict__ degp,
                                               u32* __restrict__ csr,
                                               u16* __restrict__ yh,
                                               int N, int E, int gpb) {
    int bid = blockIdx.x;
    if (bid < gpb) {
        gemm_body(x, Wh, yh, N, 1, bid, threadIdx.x);
    } else {
        int e = (bid - gpb) * 256 + threadIdx.x;
        if (e < E) {
            int s = src[e], d = dst[e];
            float nm = dis[s] * ew[e] * dis[d];
            int pos = atomicAdd(&degp[d * DEG_STRIDE], 1);
            csr[pos] = ((u32)__half_as_ushort(__float2half_rn(nm)) << 16) | (u32)s;
        }
    }
}

// One WAVE per (node, batch): grid (N, 2). Batch-phased dispatch -> 12.8MB
// working set/phase. Uniform CSR indexing (scalar s_loads). 8-deep MLP.
// STRUCTURALLY DONE (r15): random-256B gather plateau ~4 TB/s.
__global__ __launch_bounds__(64) void agg_kernel(const u32* __restrict__ yh,
                                                 const int* __restrict__ rowptr,
                                                 const u32* __restrict__ csr,
                                                 const float* __restrict__ bias,
                                                 float* __restrict__ out, int N) {
    int node = blockIdx.x;
    int b = blockIdx.y;
    int lane = threadIdx.x;                 // 0..63
    const u32* xb = yh + (size_t)b * 64 + lane;   // + node*128 (u32 units)
    int beg = rowptr[node], end = rowptr[node + 1];
    float2 acc = make_float2(0.f, 0.f);

    int j0 = beg;
    for (; j0 + 8 <= end; j0 += 8) {
        u32 pv[8];
#pragma unroll
        for (int j = 0; j < 8; ++j) pv[j] = csr[j0 + j];      // uniform -> s_load
        u32 q[8];
#pragma unroll
        for (int j = 0; j < 8; ++j) q[j] = xb[(size_t)(pv[j] & 0xffffu) * 128];
#pragma unroll
        for (int j = 0; j < 8; ++j) {
            float nm = __half2float(__ushort_as_half((u16)(pv[j] >> 16)));
            acc.x = fmaf(__uint_as_float(q[j] << 16), nm, acc.x);
            acc.y = fmaf(__uint_as_float(q[j] & 0xffff0000u), nm, acc.y);
        }
    }
    for (; j0 < end; ++j0) {
        u32 pv = csr[j0];
        float nm = __half2float(__ushort_as_half((u16)(pv >> 16)));
        u32 v = xb[(size_t)(pv & 0xffffu) * 128];
        acc.x = fmaf(__uint_as_float(v << 16), nm, acc.x);
        acc.y = fmaf(__uint_as_float(v & 0xffff0000u), nm, acc.y);
    }

    float2 bv = *(const float2*)(bias + lane * 2);
    acc.x += bv.x; acc.y += bv.y;
    *(float2*)(out + ((size_t)b * N + node) * 128 + lane * 2) = acc;
}

extern "C" void kernel_launch(void* const* d_in, const int* in_sizes, int n_in,
                              void* d_out, int out_size, void* d_ws, size_t ws_size,
                              hipStream_t stream) {
    const float* x    = (const float*)d_in[0];
    const int*   eidx = (const int*)d_in[1];   // [2][E] flat: src then dst
    const float* ew   = (const float*)d_in[2];
    const float* W    = (const float*)d_in[3];
    const float* bias = (const float*)d_in[4];
    float* out = (float*)d_out;

    const int E = in_sizes[2];                 // edge_weight count
    const int N = in_sizes[0] / 256;           // B=2, F=128 -> N = size/(2*128)
    const int nb = (N + 1023) / 1024;          // scan blocks (must be <= 256)

    const int* srcp = eidx;
    const int* dstp = eidx + E;

    // ws footprint ~31 MB — within round-3-proven envelope. DO NOT GROW (round-6 overflow).
    char* w = (char*)d_ws;
    int*   degp   = (int*)w;   w += WS_ALIGN((size_t)N * DEG_STRIDE * 4);  // padded counters/cursor
    int*   rowptr = (int*)w;   w += WS_ALIGN((size_t)(N + 1) * 4);
    float* dis    = (float*)w; w += WS_ALIGN((size_t)N * 4);
    int*   bsum   = (int*)w;   w += WS_ALIGN((size_t)nb * 4);
    u32*   csr    = (u32*)w;   w += WS_ALIGN((size_t)E * 4);        // packed 4B/edge
    u16*   yh     = (u16*)w;   w += WS_ALIGN((size_t)N * 512);      // [N][2][128] bf16
    uint2* Wh     = (uint2*)w; w += WS_ALIGN((size_t)128 * 128 * 2);

    int n4 = (N * DEG_STRIDE) / 4;             // int4 count for zeroing
    int pblk = (n4 > 4096 ? n4 : 4096);
    hipLaunchKernelGGL(prep_kernel, dim3((pblk + 255) / 256), dim3(256), 0, stream,
                       W, Wh, (int4*)degp, n4);
    int gpb = ((N + 31) / 32 + 3) / 4;                    // gemm blocks per batch
    int eBlocks = (E + 255) / 256;                        // 1 edge/thread
    hipLaunchKernelGGL(kernelA, dim3(gpb + eBlocks), dim3(256), 0, stream,
                       x, (const u16*)Wh, dstp, degp, yh, N, E, gpb);
    hipLaunchKernelGGL(scan1_kernel, dim3(nb), dim3(256), 0, stream, degp, bsum, N);
    hipLaunchKernelGGL(scan3_kernel, dim3(nb), dim3(256), 0, stream, degp, bsum, rowptr, dis, N, nb);
    hipLaunchKernelGGL(kernelB, dim3(gpb + eBlocks), dim3(256), 0, stream,
                       x, (const u16*)Wh, srcp, dstp, ew, dis, degp, csr, yh, N, E, gpb);
    hipLaunchKernelGGL(agg_kernel,  dim3(N, 2), dim3(64), 0, stream,
                       (const u32*)yh, rowptr, csr, bias, out, N);
}

// Round 24
// 139.764 us; speedup vs baseline: 1.2830x; 1.0620x over previous
//
#include <hip/hip_runtime.h>
#include <hip/hip_fp16.h>

typedef unsigned int u32;
typedef unsigned short u16;
typedef __attribute__((ext_vector_type(8))) short bf16x8;
typedef __attribute__((ext_vector_type(4))) float f32x4;

#define WS_ALIGN(x) (((x) + 255) & ~(size_t)255)
#define DEG_STRIDE 8   // ints: 32B counter spacing -> 8x less line contention

__device__ inline u16 f2bf(float f) {
    u32 u = __float_as_uint(f);
    u32 r = (u + 0x7fffu + ((u >> 16) & 1u)) >> 16;   // RNE
    return (u16)r;
}

// prep: zero padded counters (int4) + W f32 -> Wh bf16
__global__ void prep_kernel(const float* __restrict__ W, uint2* __restrict__ Wh,
                            int4* __restrict__ degp4, int n4) {
    int t = blockIdx.x * 256 + threadIdx.x;
    if (t < n4) degp4[t] = make_int4(0, 0, 0, 0);
    if (t < 4096) {
        float4 v = ((const float4*)W)[t];
        Wh[t] = make_uint2((u32)f2bf(v.x) | ((u32)f2bf(v.y) << 16),
                           (u32)f2bf(v.z) | ((u32)f2bf(v.w) << 16));
    }
}

// Shared gemm body: one wave = 32 nodes (2 m-tiles) of batch b.
// Swapped operands: A=W rows, B=x rows; identical A/B k-maps cancel the HW
// k-permutation (validated r7/r9/r10). D (m89): col=lane&15 (node), row=g*4+reg.
__device__ __forceinline__ void gemm_body(const float* __restrict__ x,
                                          const u16* __restrict__ Wh,
                                          u16* __restrict__ yh,
                                          int N, int b, int gbid, int tid) {
    int wv = gbid * 4 + (tid >> 6);
    int r0 = wv * 32;
    if (r0 >= N) return;
    int lane = tid & 63;
    int l15 = lane & 15, g = lane >> 4;

    bf16x8 xb[2][4];
#pragma unroll
    for (int m = 0; m < 2; ++m) {
        int xrow = r0 + m * 16 + l15;
        if (xrow >= N) xrow = N - 1;      // safe clamp (store is guarded)
        const float* xp = x + ((size_t)b * N + xrow) * 128 + g * 8;
#pragma unroll
        for (int kt = 0; kt < 4; ++kt) {
            float4 u0 = *(const float4*)(xp + kt * 32);
            float4 u1 = *(const float4*)(xp + kt * 32 + 4);
            bf16x8 t;
            t[0] = (short)f2bf(u0.x); t[1] = (short)f2bf(u0.y);
            t[2] = (short)f2bf(u0.z); t[3] = (short)f2bf(u0.w);
            t[4] = (short)f2bf(u1.x); t[5] = (short)f2bf(u1.y);
            t[6] = (short)f2bf(u1.z); t[7] = (short)f2bf(u1.w);
            xb[m][kt] = t;
        }
    }

    int n0 = r0 + l15, n1 = r0 + 16 + l15;
    u16* yp0 = yh + (size_t)n0 * 256 + b * 128 + g * 4;
    u16* yp1 = yh + (size_t)n1 * 256 + b * 128 + g * 4;
#pragma unroll
    for (int ct = 0; ct < 8; ++ct) {
        const u16* wp = Wh + (size_t)(ct * 16 + l15) * 128 + g * 8;
        f32x4 a0 = {0.f, 0.f, 0.f, 0.f};
        f32x4 a1 = {0.f, 0.f, 0.f, 0.f};
#pragma unroll
        for (int kt = 0; kt < 4; ++kt) {
            bf16x8 wf = *(const bf16x8*)(wp + kt * 32);
            a0 = __builtin_amdgcn_mfma_f32_16x16x32_bf16(wf, xb[0][kt], a0, 0, 0, 0);
            a1 = __builtin_amdgcn_mfma_f32_16x16x32_bf16(wf, xb[1][kt], a1, 0, 0, 0);
        }
        if (n0 < N) {
            u32 lo = (u32)f2bf(a0[0]) | ((u32)f2bf(a0[1]) << 16);
            u32 hi = (u32)f2bf(a0[2]) | ((u32)f2bf(a0[3]) << 16);
            *(uint2*)(yp0 + ct * 16) = make_uint2(lo, hi);
        }
        if (n1 < N) {
            u32 lo = (u32)f2bf(a1[0]) | ((u32)f2bf(a1[1]) << 16);
            u32 hi = (u32)f2bf(a1[2]) | ((u32)f2bf(a1[3]) << 16);
            *(uint2*)(yp1 + ct * 16) = make_uint2(lo, hi);
        }
    }
}

// Kernel A: gemm(batch 0) || deg histogram + SLOT SAVE. The atomicAdd's
// return value is each edge's within-node slot; saving it (coalesced 4B
// store) lets fill skip its atomic entirely (r23: fill's atomic->scatter
// dependent chain, not atomic throughput, was the 56µs cost).
__global__ __launch_bounds__(256) void kernelA(const float* __restrict__ x,
                                               const u16* __restrict__ Wh,
                                               const int* __restrict__ dst,
                                               int* __restrict__ degp,
                                               int* __restrict__ slots,
                                               u16* __restrict__ yh,
                                               int N, int E, int gpb) {
    int bid = blockIdx.x;
    if (bid < gpb) {
        gemm_body(x, Wh, yh, N, 0, bid, threadIdx.x);
    } else {
        int e = (bid - gpb) * 256 + threadIdx.x;
        if (e < E) slots[e] = atomicAdd(&degp[dst[e] * DEG_STRIDE], 1);
    }
}

// Block scan: per-block sums over padded deg; 4 elems/thread, Hillis-Steele.
__global__ void scan1_kernel(const int* __restrict__ degp, int* __restrict__ bsum, int N) {
    __shared__ int tmp[256];
    int tid = threadIdx.x;
    int i0 = blockIdx.x * 1024 + tid * 4;
    int s = 0;
#pragma unroll
    for (int j = 0; j < 4; ++j) if (i0 + j < N) s += degp[(i0 + j) * DEG_STRIDE];
    tmp[tid] = s;
    __syncthreads();
    for (int off = 1; off < 256; off <<= 1) {
        int t = (tid >= off) ? tmp[tid - off] : 0;
        __syncthreads();
        tmp[tid] += t;
        __syncthreads();
    }
    if (tid == 255) bsum[blockIdx.x] = tmp[255];
}

// scan3: re-scan bsum in LDS for block offset; local prefix; writes rowptr
// and dis. (No cursor needed anymore — fill uses rowptr + saved slots.)
__global__ void scan3_kernel(const int* __restrict__ degp, const int* __restrict__ bsum,
                             int* __restrict__ rowptr, float* __restrict__ dis,
                             int N, int nb) {
    __shared__ int tmp[256];
    __shared__ int bs[256];
    int tid = threadIdx.x;
    bs[tid] = (tid < nb) ? bsum[tid] : 0;
    __syncthreads();
    for (int off = 1; off < 256; off <<= 1) {
        int t = (tid >= off) ? bs[tid - off] : 0;
        __syncthreads();
        bs[tid] += t;
        __syncthreads();
    }
    int boff = bs[blockIdx.x] - bsum[blockIdx.x];

    int i0 = blockIdx.x * 1024 + tid * 4;
    int v0 = (i0 < N) ? degp[i0 * DEG_STRIDE] : 0;
    int v1 = (i0 + 1 < N) ? degp[(i0 + 1) * DEG_STRIDE] : 0;
    int v2 = (i0 + 2 < N) ? degp[(i0 + 2) * DEG_STRIDE] : 0;
    int v3 = (i0 + 3 < N) ? degp[(i0 + 3) * DEG_STRIDE] : 0;
    int s = v0 + v1 + v2 + v3;
    tmp[tid] = s;
    __syncthreads();
    for (int off = 1; off < 256; off <<= 1) {
        int t = (tid >= off) ? tmp[tid - off] : 0;
        __syncthreads();
        tmp[tid] += t;
        __syncthreads();
    }
    int e0 = tmp[tid] - s + boff;
    int e1 = e0 + v0, e2 = e1 + v1, e3 = e2 + v2;
    if (i0 < N) {
        rowptr[i0] = e0;
        dis[i0] = rsqrtf((float)(v0 < 1 ? 1 : v0));
        if (i0 == N - 1) rowptr[N] = e1;
    }
    if (i0 + 1 < N) {
        rowptr[i0 + 1] = e1;
        dis[i0 + 1] = rsqrtf((float)(v1 < 1 ? 1 : v1));
        if (i0 + 1 == N - 1) rowptr[N] = e2;
    }
    if (i0 + 2 < N) {
        rowptr[i0 + 2] = e2;
        dis[i0 + 2] = rsqrtf((float)(v2 < 1 ? 1 : v2));
        if (i0 + 2 == N - 1) rowptr[N] = e3;
    }
    if (i0 + 3 < N) {
        rowptr[i0 + 3] = e3;
        dis[i0 + 3] = rsqrtf((float)(v3 < 1 ? 1 : v3));
        if (i0 + 3 == N - 1) rowptr[N] = e3 + v3;
    }
}

// Kernel B: gemm(batch 1) || fill WITHOUT atomics: pos = rowptr[dst] +
// slots[e]. rowptr is 200KB -> L2-resident random 4B load (non-serializing)
// instead of the r23 atomic round trip.
// csr entry: 4B packed = (fp16(norm) << 16) | src  (src < 65536; N=50000).
__global__ __launch_bounds__(256) void kernelB(const float* __restrict__ x,
                                               const u16* __restrict__ Wh,
                                               const int* __restrict__ src,
                                               const int* __restrict__ dst,
                                               const float* __restrict__ ew,
                                               const float* __restrict__ dis,
                                               const int* __restrict__ rowptr,
                                               const int* __restrict__ slots,
                                               u32* __restrict__ csr,
                                               u16* __restrict__ yh,
                                               int N, int E, int gpb) {
    int bid = blockIdx.x;
    if (bid < gpb) {
        gemm_body(x, Wh, yh, N, 1, bid, threadIdx.x);
    } else {
        int e = (bid - gpb) * 256 + threadIdx.x;
        if (e < E) {
            int s = src[e], d = dst[e];
            float nm = dis[s] * ew[e] * dis[d];
            int pos = rowptr[d] + slots[e];
            csr[pos] = ((u32)__half_as_ushort(__float2half_rn(nm)) << 16) | (u32)s;
        }
    }
}

// One WAVE per (node, batch): grid (N, 2). Batch-phased dispatch -> 12.8MB
// working set/phase. Uniform CSR indexing (scalar s_loads). 8-deep MLP.
// STRUCTURALLY DONE (r15): random-256B gather plateau ~4 TB/s.
__global__ __launch_bounds__(64) void agg_kernel(const u32* __restrict__ yh,
                                                 const int* __restrict__ rowptr,
                                                 const u32* __restrict__ csr,
                                                 const float* __restrict__ bias,
                                                 float* __restrict__ out, int N) {
    int node = blockIdx.x;
    int b = blockIdx.y;
    int lane = threadIdx.x;                 // 0..63
    const u32* xb = yh + (size_t)b * 64 + lane;   // + node*128 (u32 units)
    int beg = rowptr[node], end = rowptr[node + 1];
    float2 acc = make_float2(0.f, 0.f);

    int j0 = beg;
    for (; j0 + 8 <= end; j0 += 8) {
        u32 pv[8];
#pragma unroll
        for (int j = 0; j < 8; ++j) pv[j] = csr[j0 + j];      // uniform -> s_load
        u32 q[8];
#pragma unroll
        for (int j = 0; j < 8; ++j) q[j] = xb[(size_t)(pv[j] & 0xffffu) * 128];
#pragma unroll
        for (int j = 0; j < 8; ++j) {
            float nm = __half2float(__ushort_as_half((u16)(pv[j] >> 16)));
            acc.x = fmaf(__uint_as_float(q[j] << 16), nm, acc.x);
            acc.y = fmaf(__uint_as_float(q[j] & 0xffff0000u), nm, acc.y);
        }
    }
    for (; j0 < end; ++j0) {
        u32 pv = csr[j0];
        float nm = __half2float(__ushort_as_half((u16)(pv >> 16)));
        u32 v = xb[(size_t)(pv & 0xffffu) * 128];
        acc.x = fmaf(__uint_as_float(v << 16), nm, acc.x);
        acc.y = fmaf(__uint_as_float(v & 0xffff0000u), nm, acc.y);
    }

    float2 bv = *(const float2*)(bias + lane * 2);
    acc.x += bv.x; acc.y += bv.y;
    *(float2*)(out + ((size_t)b * N + node) * 128 + lane * 2) = acc;
}

extern "C" void kernel_launch(void* const* d_in, const int* in_sizes, int n_in,
                              void* d_out, int out_size, void* d_ws, size_t ws_size,
                              hipStream_t stream) {
    const float* x    = (const float*)d_in[0];
    const int*   eidx = (const int*)d_in[1];   // [2][E] flat: src then dst
    const float* ew   = (const float*)d_in[2];
    const float* W    = (const float*)d_in[3];
    const float* bias = (const float*)d_in[4];
    float* out = (float*)d_out;

    const int E = in_sizes[2];                 // edge_weight count
    const int N = in_sizes[0] / 256;           // B=2, F=128 -> N = size/(2*128)
    const int nb = (N + 1023) / 1024;          // scan blocks (must be <= 256)

    const int* srcp = eidx;
    const int* dstp = eidx + E;

    // ws footprint ~34.4 MB (slots +3.2MB). Envelope note: r6 overflow was at
    // 58.6MB; d_out alone is 51MB so ws_size >= ~48MB — wide margin retained.
    char* w = (char*)d_ws;
    int*   degp   = (int*)w;   w += WS_ALIGN((size_t)N * DEG_STRIDE * 4);  // padded counters
    int*   rowptr = (int*)w;   w += WS_ALIGN((size_t)(N + 1) * 4);
    float* dis    = (float*)w; w += WS_ALIGN((size_t)N * 4);
    int*   bsum   = (int*)w;   w += WS_ALIGN((size_t)nb * 4);
    u32*   csr    = (u32*)w;   w += WS_ALIGN((size_t)E * 4);        // packed 4B/edge
    int*   slots  = (int*)w;   w += WS_ALIGN((size_t)E * 4);        // per-edge slot
    u16*   yh     = (u16*)w;   w += WS_ALIGN((size_t)N * 512);      // [N][2][128] bf16
    uint2* Wh     = (uint2*)w; w += WS_ALIGN((size_t)128 * 128 * 2);

    int n4 = (N * DEG_STRIDE) / 4;             // int4 count for zeroing
    int pblk = (n4 > 4096 ? n4 : 4096);
    hipLaunchKernelGGL(prep_kernel, dim3((pblk + 255) / 256), dim3(256), 0, stream,
                       W, Wh, (int4*)degp, n4);
    int gpb = ((N + 31) / 32 + 3) / 4;                    // gemm blocks per batch
    int eBlocks = (E + 255) / 256;                        // 1 edge/thread
    hipLaunchKernelGGL(kernelA, dim3(gpb + eBlocks), dim3(256), 0, stream,
                       x, (const u16*)Wh, dstp, degp, slots, yh, N, E, gpb);
    hipLaunchKernelGGL(scan1_kernel, dim3(nb), dim3(256), 0, stream, degp, bsum, N);
    hipLaunchKernelGGL(scan3_kernel, dim3(nb), dim3(256), 0, stream, degp, bsum, rowptr, dis, N, nb);
    hipLaunchKernelGGL(kernelB, dim3(gpb + eBlocks), dim3(256), 0, stream,
                       x, (const u16*)Wh, srcp, dstp, ew, dis, rowptr, slots, csr, yh, N, E, gpb);
    hipLaunchKernelGGL(agg_kernel,  dim3(N, 2), dim3(64), 0, stream,
                       (const u32*)yh, rowptr, csr, bias, out, N);
}